// Round 1
// baseline (341.633 us; speedup 1.0000x reference)
//
#include <hip/hip_runtime.h>
#include <cstddef>

#define NROWS 16384
#define NCOLS 2048
#define CPG   16
#define NGRP  128
#define EPS_W 1e-5f
#define NS_T  5

#define TROWS 32
#define CHUNKS 32               // stats row chunks (blockIdx.y)
#define RPB (NROWS / CHUNKS)    // 512 rows per stats block
#define NT_STATS (RPB / TROWS)  // 16 tiles
#define ASTRIPES 64             // apply row stripes
#define RPA (NROWS / ASTRIPES)  // 256 rows per apply block
#define NT_APPLY (RPA / TROWS)  // 8 tiles

#define PART_STRIDE 272         // 16 mean sums + 256 second moments

__device__ __forceinline__ float dot4(float4 p, float4 v) {
  return p.x * v.x + p.y * v.y + p.z * v.z + p.w * v.w;
}

// ---------------- Phase 1: per-group mean + second-moment partials ----------------
__global__ __launch_bounds__(256) void k_stats(const float* __restrict__ x,
                                               float* __restrict__ part) {
  __shared__ __align__(16) float tile[2][TROWS * 256];
  const int cb   = blockIdx.x;      // 0..7 column block (16 groups)
  const int ch   = blockIdx.y;      // 0..31 row chunk
  const int t    = threadIdx.x;
  const int col0 = cb << 8;
  const int r0   = ch * RPB;

  const int g  = t >> 4;            // group within block 0..15
  const int ti = t & 15;            // 4x4 tile id
  const int tc = (ti >> 2) << 2;    // row quad of cov tile
  const int td = (ti & 3) << 2;     // col quad of cov tile

  float mac = 0.f;                  // mean accumulator for column col0+t
  float acc00 = 0.f, acc01 = 0.f, acc02 = 0.f, acc03 = 0.f;
  float acc10 = 0.f, acc11 = 0.f, acc12 = 0.f, acc13 = 0.f;
  float acc20 = 0.f, acc21 = 0.f, acc22 = 0.f, acc23 = 0.f;
  float acc30 = 0.f, acc31 = 0.f, acc32 = 0.f, acc33 = 0.f;

  float4 st[8];
  // prologue: stage tile 0
#pragma unroll
  for (int i = 0; i < 8; ++i) {
    const int f = (i << 8) | t;
    const int r = f >> 6, cq = f & 63;
    st[i] = *(const float4*)(x + (size_t)(r0 + r) * NCOLS + col0 + (cq << 2));
  }
#pragma unroll
  for (int i = 0; i < 8; ++i) {
    const int f = (i << 8) | t;
    *(float4*)(&tile[0][f << 2]) = st[i];
  }
  __syncthreads();

  int cur = 0;
  for (int tb = 0; tb < NT_STATS; ++tb) {
    const bool hn = (tb + 1 < NT_STATS);
    if (hn) {
      const int rn = r0 + (tb + 1) * TROWS;
#pragma unroll
      for (int i = 0; i < 8; ++i) {
        const int f = (i << 8) | t;
        const int r = f >> 6, cq = f & 63;
        st[i] = *(const float4*)(x + (size_t)(rn + r) * NCOLS + col0 + (cq << 2));
      }
    }
    const float* __restrict__ buf = tile[cur];
#pragma unroll 4
    for (int r = 0; r < TROWS; ++r) {
      const float* row = buf + r * 256;
      mac += row[t];
      const float* rg = row + (g << 4);
      const float4 xa = *(const float4*)(rg + tc);
      const float4 xb = *(const float4*)(rg + td);
      acc00 += xa.x * xb.x; acc01 += xa.x * xb.y; acc02 += xa.x * xb.z; acc03 += xa.x * xb.w;
      acc10 += xa.y * xb.x; acc11 += xa.y * xb.y; acc12 += xa.y * xb.z; acc13 += xa.y * xb.w;
      acc20 += xa.z * xb.x; acc21 += xa.z * xb.y; acc22 += xa.z * xb.z; acc23 += xa.z * xb.w;
      acc30 += xa.w * xb.x; acc31 += xa.w * xb.y; acc32 += xa.w * xb.z; acc33 += xa.w * xb.w;
    }
    if (hn) {
#pragma unroll
      for (int i = 0; i < 8; ++i) {
        const int f = (i << 8) | t;
        *(float4*)(&tile[cur ^ 1][f << 2]) = st[i];
      }
    }
    __syncthreads();
    cur ^= 1;
  }

  float* p = part + ((size_t)ch * NGRP + (cb << 4) + g) * PART_STRIDE;
  p[ti] = mac;  // column col0+t == (group cb*16+g, channel ti)
  const int base = 16 + tc * 16 + td;
  p[base + 0 * 16 + 0] = acc00; p[base + 0 * 16 + 1] = acc01; p[base + 0 * 16 + 2] = acc02; p[base + 0 * 16 + 3] = acc03;
  p[base + 1 * 16 + 0] = acc10; p[base + 1 * 16 + 1] = acc11; p[base + 1 * 16 + 2] = acc12; p[base + 1 * 16 + 3] = acc13;
  p[base + 2 * 16 + 0] = acc20; p[base + 2 * 16 + 1] = acc21; p[base + 2 * 16 + 2] = acc22; p[base + 2 * 16 + 3] = acc23;
  p[base + 3 * 16 + 0] = acc30; p[base + 3 * 16 + 1] = acc31; p[base + 3 * 16 + 2] = acc32; p[base + 3 * 16 + 3] = acc33;
}

// ---------------- Phase 2: reduce partials, Newton-Schulz, fold scalars ----------------
__global__ __launch_bounds__(256) void k_ns(const float* __restrict__ part,
                                            const float* __restrict__ swm,
                                            const float* __restrict__ swv,
                                            const float* __restrict__ wgt,
                                            const float* __restrict__ bia,
                                            float* __restrict__ A2,
                                            float* __restrict__ b2) {
  __shared__ float sP[256], sA[256], sB[256], sN[256], smean[16];
  __shared__ float strace;
  const int G = blockIdx.x;
  const int t = threadIdx.x;
  const int c = t >> 4, d = t & 15;

  float m2 = 0.f;
  for (int ch = 0; ch < CHUNKS; ++ch)
    m2 += part[((size_t)ch * NGRP + G) * PART_STRIDE + 16 + t];
  if (t < 16) {
    float ms = 0.f;
    for (int ch = 0; ch < CHUNKS; ++ch)
      ms += part[((size_t)ch * NGRP + G) * PART_STRIDE + t];
    smean[t] = ms * (1.f / NROWS);
  }
  __syncthreads();

  // softmax of the two 2-element weight vectors (computed redundantly per thread)
  const float a0 = swm[0], a1 = swm[1];
  const float am = fmaxf(a0, a1);
  const float e0 = expf(a0 - am), e1 = expf(a1 - am);
  const float mw0 = e0 / (e0 + e1), mw1 = e1 / (e0 + e1);
  const float v0 = swv[0], v1 = swv[1];
  const float vm = fmaxf(v0, v1);
  const float f0 = expf(v0 - vm), f1 = expf(v1 - vm);
  const float vw0 = f0 / (f0 + f1);

  float cov = m2 * (1.f / NROWS) - smean[c] * smean[d];
  cov = vw0 * cov + ((c == d) ? EPS_W : 0.f);
  sN[t] = cov;
  __syncthreads();
  if (t == 0) {
    float tr = 0.f;
#pragma unroll
    for (int k = 0; k < 16; ++k) tr += sN[k * 17];
    strace = 1.f / tr;
  }
  __syncthreads();
  const float rTr = strace;
  sN[t] = cov * rTr;               // covN
  sP[t] = (c == d) ? 1.f : 0.f;    // P = I
  __syncthreads();

  for (int it = 0; it < NS_T; ++it) {
    float p2 = 0.f;
#pragma unroll
    for (int k = 0; k < 16; ++k) p2 += sP[c * 16 + k] * sP[k * 16 + d];
    sA[t] = p2;
    __syncthreads();
    float p3 = 0.f;
#pragma unroll
    for (int k = 0; k < 16; ++k) p3 += sA[c * 16 + k] * sP[k * 16 + d];
    sB[t] = p3;
    __syncthreads();
    float qv = 0.f;
#pragma unroll
    for (int k = 0; k < 16; ++k) qv += sB[c * 16 + k] * sN[k * 16 + d];
    const float np = 1.5f * sP[t] - 0.5f * qv;
    __syncthreads();
    sP[t] = np;
    __syncthreads();
  }

  const float wmv = sP[t] * sqrtf(rTr);
  const float wr = wgt[(G << 4) + c];
  A2[(size_t)G * 256 + t] = wmv * (1.f - mw1) * wr;   // (1-mw1)*wm, scaled by weight[row]
  sA[t] = wmv * smean[d];
  __syncthreads();
  if (t < 16) {
    float s = 0.f;
#pragma unroll
    for (int k = 0; k < 16; ++k) s += sA[t * 16 + k];
    b2[(G << 4) + t] = -mw0 * s * wgt[(G << 4) + t] + bia[(G << 4) + t];
  }
}

// ---------------- Phase 3: y = A2 @ x_row + b2 (per group), fused affine ----------------
__global__ __launch_bounds__(256) void k_apply(const float* __restrict__ x,
                                               const float* __restrict__ A2,
                                               const float* __restrict__ b2,
                                               float* __restrict__ y) {
  __shared__ __align__(16) float tile[2][TROWS * 256];
  const int cb   = blockIdx.x;   // 0..7
  const int stb  = blockIdx.y;   // 0..63
  const int t    = threadIdx.x;
  const int col0 = cb << 8;
  const int r0   = stb * RPA;

  const int w  = t >> 6, l = t & 63;
  const int g  = (w << 2) | (l >> 4);  // 0..15
  const int q  = (l >> 2) & 3;         // output quad 0..3
  const int rp = l & 3;                // row phase 0..3
  const int G  = (cb << 4) | g;

  float4 a[4][4];
#pragma unroll
  for (int i = 0; i < 4; ++i)
#pragma unroll
    for (int dq = 0; dq < 4; ++dq)
      a[i][dq] = *(const float4*)(A2 + (size_t)G * 256 + ((q << 2) + i) * 16 + (dq << 2));
  float bv[4];
#pragma unroll
  for (int i = 0; i < 4; ++i) bv[i] = b2[(G << 4) + (q << 2) + i];

  float4 st[8];
#pragma unroll
  for (int i = 0; i < 8; ++i) {
    const int f = (i << 8) | t;
    const int r = f >> 6, cq = f & 63;
    st[i] = *(const float4*)(x + (size_t)(r0 + r) * NCOLS + col0 + (cq << 2));
  }
#pragma unroll
  for (int i = 0; i < 8; ++i) {
    const int f = (i << 8) | t;
    *(float4*)(&tile[0][f << 2]) = st[i];
  }
  __syncthreads();

  int cur = 0;
  for (int tb = 0; tb < NT_APPLY; ++tb) {
    const bool hn = (tb + 1 < NT_APPLY);
    if (hn) {
      const int rn = r0 + (tb + 1) * TROWS;
#pragma unroll
      for (int i = 0; i < 8; ++i) {
        const int f = (i << 8) | t;
        const int r = f >> 6, cq = f & 63;
        st[i] = *(const float4*)(x + (size_t)(rn + r) * NCOLS + col0 + (cq << 2));
      }
    }
    const float* __restrict__ buf = tile[cur];
    const int rbase = r0 + tb * TROWS;
#pragma unroll
    for (int r = rp; r < TROWS; r += 4) {
      const float* xr = buf + r * 256 + (g << 4);
      const float4 xv0 = *(const float4*)(xr + 0);
      const float4 xv1 = *(const float4*)(xr + 4);
      const float4 xv2 = *(const float4*)(xr + 8);
      const float4 xv3 = *(const float4*)(xr + 12);
      const float s0 = bv[0] + dot4(a[0][0], xv0) + dot4(a[0][1], xv1) + dot4(a[0][2], xv2) + dot4(a[0][3], xv3);
      const float s1 = bv[1] + dot4(a[1][0], xv0) + dot4(a[1][1], xv1) + dot4(a[1][2], xv2) + dot4(a[1][3], xv3);
      const float s2 = bv[2] + dot4(a[2][0], xv0) + dot4(a[2][1], xv1) + dot4(a[2][2], xv2) + dot4(a[2][3], xv3);
      const float s3 = bv[3] + dot4(a[3][0], xv0) + dot4(a[3][1], xv1) + dot4(a[3][2], xv2) + dot4(a[3][3], xv3);
      *(float4*)(y + (size_t)(rbase + r) * NCOLS + col0 + (g << 4) + (q << 2)) =
          make_float4(s0, s1, s2, s3);
    }
    if (hn) {
#pragma unroll
      for (int i = 0; i < 8; ++i) {
        const int f = (i << 8) | t;
        *(float4*)(&tile[cur ^ 1][f << 2]) = st[i];
      }
    }
    __syncthreads();
    cur ^= 1;
  }
}

extern "C" void kernel_launch(void* const* d_in, const int* in_sizes, int n_in,
                              void* d_out, int out_size, void* d_ws, size_t ws_size,
                              hipStream_t stream) {
  (void)in_sizes; (void)n_in; (void)out_size; (void)ws_size;
  const float* x   = (const float*)d_in[0];
  const float* swm = (const float*)d_in[1];
  const float* swv = (const float*)d_in[2];
  const float* wgt = (const float*)d_in[3];
  const float* bia = (const float*)d_in[4];
  float* out = (float*)d_out;

  float* part = (float*)d_ws;                        // 32*128*272 floats = 4.46 MB
  float* A2   = part + (size_t)CHUNKS * NGRP * PART_STRIDE;
  float* b2   = A2 + (size_t)NGRP * 256;

  k_stats<<<dim3(8, CHUNKS), 256, 0, stream>>>(x, part);
  k_ns<<<NGRP, 256, 0, stream>>>(part, swm, swv, wgt, bia, A2, b2);
  k_apply<<<dim3(8, ASTRIPES), 256, 0, stream>>>(x, A2, b2, out);
}